// Round 7
// baseline (379.896 us; speedup 1.0000x reference)
//
#include <hip/hip_runtime.h>
#include <hip/hip_bf16.h>
#include <math.h>

// Problem constants
#define B_    16
#define HID   64
#define CIN   32
#define OC1   192   // 3*HID
#define CCC   16    // 2*CONNECTION
#define HW_   128
#define NPIX  (HW_*HW_)

typedef _Float16 half8 __attribute__((ext_vector_type(8)));    // 8 fp16
typedef _Float16 half4 __attribute__((ext_vector_type(4)));    // 4 fp16 (8 B)
typedef float floatx4 __attribute__((ext_vector_type(4)));     // MFMA C/D

// ---- sortable-uint encoding for float atomicMin/Max ----
__device__ __forceinline__ unsigned fenc(float f) {
    unsigned b = __float_as_uint(f);
    return (b & 0x80000000u) ? ~b : (b | 0x80000000u);
}
__device__ __forceinline__ float fdec(unsigned u) {
    unsigned b = (u & 0x80000000u) ? (u ^ 0x80000000u) : ~u;
    return __uint_as_float(b);
}

// ---------------------------------------------------------------------------
// K0: repack weights + init minmax
//  wsub_f16[sk=s*3+kc][lane][j] fp16 : A-frags conv_sub (75*64*8)
//  bsum    [o] = sum_i b_proj[i][o]  : 192 fp32
//  win_f16 [s][mt][lane][j] fp16     : A-frags conv_in  (9*12*64*8)
//  wp_f16  [kt][mt][lane][j] fp16    : A-frags warp proj (8*12*64*8)
// ---------------------------------------------------------------------------
__global__ __launch_bounds__(256) void repack_kernel(
    const float* __restrict__ w_in, const float* __restrict__ w_sub,
    const float* __restrict__ w_proj, const float* __restrict__ b_proj,
    _Float16* __restrict__ wsub_f16, float* __restrict__ bsum,
    _Float16* __restrict__ win_f16, _Float16* __restrict__ wp_f16,
    unsigned* __restrict__ minmax)
{
    int idx = blockIdx.x * 256 + threadIdx.x;
    if (idx < 38400) {                       // wsub_f16 frags
        int sk = idx >> 9, r2 = idx & 511;
        int l = r2 >> 3, j = r2 & 7;
        int s = sk / 3, kc = sk - s * 3;
        int ky = s / 5, kx = s - ky * 5;
        int oc = l & 15;
        int icg = kc * 32 + (l >> 4) * 8 + j;
        wsub_f16[idx] = (_Float16)w_sub[oc * 2400 + icg * 25 + ky * 5 + kx];
    } else if (idx < 38400 + 192) {
        int o = idx - 38400;
        bsum[o] = b_proj[o] + b_proj[192 + o] + b_proj[384 + o] + b_proj[576 + o];
    } else if (idx < 38592 + 55296) {        // win_f16
        int j2 = idx - 38592;
        int s = j2 / 6144, r = j2 - s * 6144;
        int mt = r / 512, r2 = r - mt * 512;
        int l = r2 >> 3, j = r2 & 7;
        int oc = mt * 16 + (l & 15);
        int ic = (l >> 4) * 8 + j;
        win_f16[j2] = (_Float16)w_in[oc * 288 + ic * 9 + s];
    } else if (idx < 38592 + 55296 + 49152) { // wp_f16
        int j3 = idx - (38592 + 55296);
        int kt = j3 / 6144, r = j3 - kt * 6144;
        int mt = r / 512, r2 = r - mt * 512;
        int l = r2 >> 3, j = r2 & 7;
        int o = mt * 16 + (l & 15);
        int c_all = kt * 32 + (l >> 4) * 8 + j;
        int i = c_all >> 6, c = c_all & 63;
        wp_f16[j3] = (_Float16)w_proj[(i * 192 + o) * 64 + c];
    }
    if (idx == 0) { minmax[0] = 0xFFFFFFFFu; minmax[1] = 0u; }
}

// ---------------------------------------------------------------------------
// K0c: channels-last fp16 repacks:
//   hcl16[b][y][x][c 0..63]  from h_prev
//   xcl16[b][y][x][c 0..31]  from x
// ---------------------------------------------------------------------------
__global__ __launch_bounds__(256) void transpose_h_kernel(
    const float* __restrict__ hp, const float* __restrict__ x,
    _Float16* __restrict__ hcl, _Float16* __restrict__ xcl)
{
    __shared__ float lds[64 * 129];   // 33024 B
    int tid = threadIdx.x;
    int y = blockIdx.x, b = blockIdx.y;

    // ---- h: 64 ch ----
    const float* hb = hp + (size_t)b * HID * NPIX + y * HW_;
#pragma unroll
    for (int it = 0; it < 32; ++it) {
        int idx = tid + it * 256;
        int c = idx >> 7, xx = idx & 127;
        lds[c * 129 + xx] = hb[(size_t)c * NPIX + xx];
    }
    __syncthreads();
    unsigned* o = (unsigned*)(hcl + (size_t)((b * HW_ + y) * HW_) * 64);
#pragma unroll
    for (int it = 0; it < 16; ++it) {
        int e2 = tid + it * 256;          // pair index: xx*32 + c2
        int c2 = e2 & 31, xx = e2 >> 5;
        union { _Float16 h[2]; unsigned u; } pk;
        pk.h[0] = (_Float16)lds[(c2 * 2) * 129 + xx];
        pk.h[1] = (_Float16)lds[(c2 * 2 + 1) * 129 + xx];
        o[e2] = pk.u;
    }
    __syncthreads();

    // ---- x: 32 ch ----
    const float* xb = x + (size_t)b * CIN * NPIX + y * HW_;
#pragma unroll
    for (int it = 0; it < 16; ++it) {
        int idx = tid + it * 256;
        int c = idx >> 7, xx = idx & 127;
        lds[c * 129 + xx] = xb[(size_t)c * NPIX + xx];
    }
    __syncthreads();
    unsigned* ox = (unsigned*)(xcl + (size_t)((b * HW_ + y) * HW_) * 32);
#pragma unroll
    for (int it = 0; it < 8; ++it) {
        int e2 = tid + it * 256;          // pair index: xx*16 + c2
        int c2 = e2 & 15, xx = e2 >> 4;
        union { _Float16 h[2]; unsigned u; } pk;
        pk.h[0] = (_Float16)lds[(c2 * 2) * 129 + xx];
        pk.h[1] = (_Float16)lds[(c2 * 2 + 1) * 129 + xx];
        ox[e2] = pk.u;
    }
}

// ---------------------------------------------------------------------------
// K1: conv_sub ONLY (5x5, 96->16), fp16 MFMA, staged from channels-last
//   hcl16/xcl16 with fully coalesced uint4 copies.
//   Tile [yy 0..11][xx 0..19][ch 0..95 pad 104]; px stride 208 B.
//   conv_sub: wave w owns px-rows {2w,2w+1}; 25*3*2 = 150 MFMAs.
// ---------------------------------------------------------------------------
__global__ __launch_bounds__(256) void conv_sub_mfma(
    const _Float16* __restrict__ xcl, const _Float16* __restrict__ hcl,
    const _Float16* __restrict__ wsub_f16, const float* __restrict__ b_sub,
    float* __restrict__ cc, unsigned* __restrict__ minmax)
{
    __shared__ __align__(16) _Float16 tile[12 * 20 * 104];  // 49920 B
    __shared__ float redmn[4], redmx[4];
    int tid = threadIdx.x;
    int b = blockIdx.z;
    int y0 = blockIdx.y * 8, x0 = blockIdx.x * 16;

    // ---- stage h channels (ch 32..95): 1920 uint4, coalesced ----
#pragma unroll
    for (int it = 0; it < 8; ++it) {
        int idx = tid + it * 256;
        if (idx < 1920) {
            int yy = idx / 160, rem = idx - yy * 160;
            int px = rem >> 3, q = rem & 7;
            int gy = y0 + yy - 2, gx = x0 + px - 2;
            bool ok = ((unsigned)gy < 128u) & ((unsigned)gx < 128u);
            int cgy = min(max(gy, 0), 127), cgx = min(max(gx, 0), 127);
            uint4 v = ((const uint4*)hcl)[(size_t)((b * 128 + cgy) * 128 + cgx) * 8 + q];
            if (!ok) { v.x = 0; v.y = 0; v.z = 0; v.w = 0; }
            *(uint4*)((char*)tile + (yy * 20 + px) * 208 + 64 + q * 16) = v;
        }
    }
    // ---- stage x channels (ch 0..31): 960 uint4, coalesced ----
#pragma unroll
    for (int it = 0; it < 4; ++it) {
        int idx = tid + it * 256;
        if (idx < 960) {
            int yy = idx / 80, rem = idx - yy * 80;
            int px = rem >> 2, q = rem & 3;
            int gy = y0 + yy - 2, gx = x0 + px - 2;
            bool ok = ((unsigned)gy < 128u) & ((unsigned)gx < 128u);
            int cgy = min(max(gy, 0), 127), cgx = min(max(gx, 0), 127);
            uint4 v = ((const uint4*)xcl)[(size_t)((b * 128 + cgy) * 128 + cgx) * 4 + q];
            if (!ok) { v.x = 0; v.y = 0; v.z = 0; v.w = 0; }
            *(uint4*)((char*)tile + (yy * 20 + px) * 208 + q * 16) = v;
        }
    }
    __syncthreads();

    int w = tid >> 6, l = tid & 63;
    int quad = l >> 4, ln = l & 15;

    floatx4 sinit;
#pragma unroll
    for (int r = 0; r < 4; ++r) sinit[r] = b_sub[quad * 4 + r];
    floatx4 sacc[2] = {sinit, sinit};

#pragma unroll 5
    for (int s = 0; s < 25; ++s) {
        int ky = s / 5, kx = s - (s / 5) * 5;
#pragma unroll
        for (int kc = 0; kc < 3; ++kc) {
            half8 af = *(const half8*)(wsub_f16 + (size_t)((s * 3 + kc) * 64 + l) * 8);
#pragma unroll
            for (int t = 0; t < 2; ++t) {
                int pos = (w * 2 + t + ky) * 20 + (ln + kx);
                half8 bf = *(const half8*)(tile + pos * 104 + kc * 32 + quad * 8);
                sacc[t] = __builtin_amdgcn_mfma_f32_16x16x32_f16(af, bf, sacc[t], 0, 0, 0);
            }
        }
    }

    // epilogue: store cc + fused min/max
    {
        float mn = 1e30f, mx = -1e30f;
#pragma unroll
        for (int t = 0; t < 2; ++t) {
            int yg = y0 + w * 2 + t;
#pragma unroll
            for (int r = 0; r < 4; ++r) {
                int oc = quad * 4 + r;
                float v = sacc[t][r];
                cc[((size_t)(b * CCC + oc) * HW_ + yg) * HW_ + x0 + ln] = v;
                mn = fminf(mn, v); mx = fmaxf(mx, v);
            }
        }
#pragma unroll
        for (int m = 1; m < 64; m <<= 1) {
            mn = fminf(mn, __shfl_xor(mn, m, 64));
            mx = fmaxf(mx, __shfl_xor(mx, m, 64));
        }
        if (l == 0) { redmn[w] = mn; redmx[w] = mx; }
    }
    __syncthreads();
    if (tid == 0) {
        float bmn = fminf(fminf(redmn[0], redmn[1]), fminf(redmn[2], redmn[3]));
        float bmx = fmaxf(fmaxf(redmx[0], redmx[1]), fmaxf(redmx[2], redmx[3]));
        atomicMin(&minmax[0], fenc(bmn));
        atomicMax(&minmax[1], fenc(bmx));
    }
}

// ---------------------------------------------------------------------------
// K3: FUSED conv_in (3x3, 32->192) + grid_sample(4 warps) + MFMA projection
//   + GRU gates.
//   STRUCTURED GATHER v2 (no __shfl): 8 consecutive lanes load 8x16-B chunks
//   of the SAME 128-B hcl record (full line utilization). Per-pixel records
//   + blend weights are redistributed through a dedicated LDS table
//   (mrec/mw, written before bar1, never overwritten) instead of
//   cross-lane shuffles. Corners 00/01 hoisted above the conv_in MFMA
//   phase; corners 10/11 + blend after bar2. Layout of warped is identical
//   to the R4-proven mapping: chunk c of pixel p at slot (c ^ (p&7)).
// ---------------------------------------------------------------------------
__global__ __launch_bounds__(256, 3) void warp_gru_conv(
    const _Float16* __restrict__ hcl, const _Float16* __restrict__ xcl,
    const float* __restrict__ cc,
    const _Float16* __restrict__ wp_f16, const float* __restrict__ bsum,
    const _Float16* __restrict__ win_f16, const float* __restrict__ b_in,
    const unsigned* __restrict__ minmax, float* __restrict__ out)
{
    __shared__ __align__(16) _Float16 smem[64 * 256];  // 32768 B; xt/warped/ol
    __shared__ __align__(16) int   mrec[256 * 4];      // 4096 B: per-thread 4 recs
    __shared__ __align__(16) float mw[256 * 4];        // 4096 B: per-thread 4 wts
    _Float16* xt = smem;        // [row 0..2][px 0..71][ic 0..31], swizzled
    _Float16* warped = smem;    // [px 0..63][ch 0..255], swizzled
    float* ol = (float*)smem;   // [ch 0..63][px 0..63], stride 68 floats

    int tid = threadIdx.x;
    int i = tid >> 6;
    int p = tid & 63;
    int b = blockIdx.z, y = blockIdx.y, xh = blockIdx.x;
    int xg = xh * 64 + p;
    int w = i, l = p;
    int quad = l >> 4, ln = l & 15;

    // ---- issue x-tile loads ----
    uint4 xv0, xv1, xv2, xv3;
    int xslot = -1;
    if (tid < 216) {
        int row = tid / 72, px = tid - row * 72;
        int gy = y - 1 + row, gx = xh * 64 - 4 + px;
        bool ok = ((unsigned)gy < 128u) & ((unsigned)gx < 128u);
        int cgy = min(max(gy, 0), 127), cgx = min(max(gx, 0), 127);
        const uint4* s = (const uint4*)(xcl + (size_t)((b * 128 + cgy) * 128 + cgx) * 32);
        xv0 = s[0]; xv1 = s[1]; xv2 = s[2]; xv3 = s[3];
        if (!ok) {
            xv0.x = xv0.y = xv0.z = xv0.w = 0; xv1 = xv0; xv2 = xv0; xv3 = xv0;
        }
        xslot = (row * 72 + px) * 4;
    }

    // ---- gate h_prev loads from hcl16 ----
    const _Float16* hclb = hcl + (size_t)b * NPIX * 64;
    half4 hpv16[4];
    {
        const _Float16* grow = hclb + (size_t)(y * HW_ + xh * 64) * 64 + 16 * w + quad * 4;
#pragma unroll
        for (int nt = 0; nt < 4; ++nt)
            hpv16[nt] = *(const half4*)(grow + (size_t)(nt * 16 + ln) * 64);
    }

    // ---- grid math for own pixel p; stash records + weights in LDS ----
    {
        float mn = fdec(minmax[0]), mx = fdec(minmax[1]);
        float scale = 2.0f / (mx - mn);
        int ccbase = ((b * CCC + 2 * i) * HW_ + y) * HW_ + xg;
        float gxn = (cc[ccbase] - mn) * scale - 1.0f;
        float gyn = (cc[ccbase + NPIX] - mn) * scale - 1.0f;
        float gx = (gxn + 1.0f) * 64.0f - 0.5f;
        float gy = (gyn + 1.0f) * 64.0f - 0.5f;
        float x0f = floorf(gx), y0f = floorf(gy);
        float wx1 = gx - x0f, wy1 = gy - y0f;
        float wx0 = 1.0f - wx1, wy0 = 1.0f - wy1;
        int ix0 = (int)x0f, iy0 = (int)y0f;
        int ix1 = ix0 + 1, iy1 = iy0 + 1;
        bool vx0 = (unsigned)ix0 < 128u, vx1 = (unsigned)ix1 < 128u;
        bool vy0 = (unsigned)iy0 < 128u, vy1 = (unsigned)iy1 < 128u;
        float w00 = (vx0 && vy0) ? wy0 * wx0 : 0.f;
        float w01 = (vx1 && vy0) ? wy0 * wx1 : 0.f;
        float w10 = (vx0 && vy1) ? wy1 * wx0 : 0.f;
        float w11 = (vx1 && vy1) ? wy1 * wx1 : 0.f;
        int cx0 = min(max(ix0, 0), 127), cx1 = min(max(ix1, 0), 127);
        int cy0 = min(max(iy0, 0), 127), cy1 = min(max(iy1, 0), 127);
        int* mr = &mrec[tid * 4];
        mr[0] = cy0 * HW_ + cx0; mr[1] = cy0 * HW_ + cx1;
        mr[2] = cy1 * HW_ + cx0; mr[3] = cy1 * HW_ + cx1;
        float* mwp = &mw[tid * 4];
        mwp[0] = w00; mwp[1] = w01; mwp[2] = w10; mwp[3] = w11;
    }

    // ---- write x tile (swizzled) ----
    if (xslot >= 0) {
        unsigned b0 = (unsigned)(xslot * 16);
        unsigned by0_ = b0 ^ (((b0 >> 7) & 3) << 4);
        unsigned b1 = (unsigned)((xslot + 1) * 16);
        unsigned by1_ = b1 ^ (((b1 >> 7) & 3) << 4);
        unsigned b2 = (unsigned)((xslot + 2) * 16);
        unsigned by2_ = b2 ^ (((b2 >> 7) & 3) << 4);
        unsigned b3 = (unsigned)((xslot + 3) * 16);
        unsigned by3_ = b3 ^ (((b3 >> 7) & 3) << 4);
        *(uint4*)((char*)xt + by0_) = xv0;
        *(uint4*)((char*)xt + by1_) = xv1;
        *(uint4*)((char*)xt + by2_) = xv2;
        *(uint4*)((char*)xt + by3_) = xv3;
    }
    __syncthreads();   // bar1: xt + mrec/mw ready

    // ---- structured gather, corners 00/01 (hoisted above conv_in) ----
    int sub = p >> 3;          // pixel sub-index within each iteration
    int e   = p & 7;           // 16-B chunk within the 128-B record
    half8 g0[8], g1[8];
#pragma unroll
    for (int it = 0; it < 8; ++it) {
        int pp = it * 8 + sub;
        const int* mr = &mrec[(i * 64 + pp) * 4];
        int r0 = mr[0], r1 = mr[1];
        g0[it] = *(const half8*)(hclb + (size_t)r0 * 64 + e * 8);
        g1[it] = *(const half8*)(hclb + (size_t)r1 * 64 + e * 8);
    }

    // ---- accumulators: z,r shared between conv_in and proj; h split ----
    floatx4 accA[3][4];   // [0]=z sum, [1]=r sum, [2]=x_h
    floatx4 hh[4];        // h_h (proj)
#pragma unroll
    for (int t = 0; t < 2; ++t) {
        floatx4 bi = *(const floatx4*)(b_in + t * 64 + 16 * w + quad * 4);
        floatx4 bs = *(const floatx4*)(bsum + t * 64 + 16 * w + quad * 4);
        floatx4 init;
#pragma unroll
        for (int r = 0; r < 4; ++r) init[r] = bi[r] + bs[r];
#pragma unroll
        for (int nt = 0; nt < 4; ++nt) accA[t][nt] = init;
    }
    {
        floatx4 bih = *(const floatx4*)(b_in + 128 + 16 * w + quad * 4);
        floatx4 bsh = *(const floatx4*)(bsum + 128 + 16 * w + quad * 4);
#pragma unroll
        for (int nt = 0; nt < 4; ++nt) { accA[2][nt] = bih; hh[nt] = bsh; }
    }

    // ---- conv_in: 9 taps x 3 m-tiles x 4 n-tiles = 108 MFMA ----
#pragma unroll
    for (int s = 0; s < 9; ++s) {
        int ky = s / 3, kx = s - ky * 3;
        half8 af[3];
#pragma unroll
        for (int t = 0; t < 3; ++t)
            af[t] = *(const half8*)(win_f16 + (size_t)((s * 12 + (t * 4 + w)) * 64 + l) * 8);
#pragma unroll
        for (int nt = 0; nt < 4; ++nt) {
            int pxr = ky * 72 + nt * 16 + ln + kx + 3;
            unsigned byte = (unsigned)(pxr * 64 + quad * 16);
            byte ^= ((byte >> 7) & 3) << 4;
            half8 bf = *(const half8*)((char*)xt + byte);
#pragma unroll
            for (int t = 0; t < 3; ++t)
                accA[t][nt] = __builtin_amdgcn_mfma_f32_16x16x32_f16(af[t], bf, accA[t][nt], 0, 0, 0);
        }
    }
    __syncthreads();   // bar2: all xt reads done; safe to overwrite with warped

    // ---- structured gather corners 10/11 + packed-fp16 blend + write ----
#pragma unroll
    for (int it = 0; it < 8; ++it) {
        int pp = it * 8 + sub;
        const int* mr = &mrec[(i * 64 + pp) * 4];
        const float* mwp = &mw[(i * 64 + pp) * 4];
        int r2 = mr[2], r3 = mr[3];
        _Float16 f00 = (_Float16)mwp[0];
        _Float16 f01 = (_Float16)mwp[1];
        _Float16 f10 = (_Float16)mwp[2];
        _Float16 f11 = (_Float16)mwp[3];
        half8 c10 = *(const half8*)(hclb + (size_t)r2 * 64 + e * 8);
        half8 c11 = *(const half8*)(hclb + (size_t)r3 * 64 + e * 8);
        half8 v = g0[it] * f00 + g1[it] * f01 + c10 * f10 + c11 * f11;
        int cs = (i * 8 + e) ^ sub;
        *(half8*)(warped + pp * 256 + cs * 8) = v;
    }
    __syncthreads();   // bar3: warped ready

    // ---- warp projection: 8 kt x 3 m x 4 n = 96 MFMA ----
#pragma unroll
    for (int kt = 0; kt < 8; ++kt) {
        half8 af[3];
#pragma unroll
        for (int t = 0; t < 3; ++t)
            af[t] = *(const half8*)(wp_f16 + (size_t)((kt * 12 + (t * 4 + w)) * 64 + l) * 8);
#pragma unroll
        for (int nt = 0; nt < 4; ++nt) {
            int pxi = nt * 16 + ln;
            int cs = (kt * 4 + quad) ^ (pxi & 7);
            half8 bf = *(const half8*)(warped + pxi * 256 + cs * 8);
            accA[0][nt] = __builtin_amdgcn_mfma_f32_16x16x32_f16(af[0], bf, accA[0][nt], 0, 0, 0);
            accA[1][nt] = __builtin_amdgcn_mfma_f32_16x16x32_f16(af[1], bf, accA[1][nt], 0, 0, 0);
            hh[nt]      = __builtin_amdgcn_mfma_f32_16x16x32_f16(af[2], bf, hh[nt], 0, 0, 0);
        }
    }

    // ---- gates (all register inputs) ----
    float gout[4][4];
#pragma unroll
    for (int nt = 0; nt < 4; ++nt) {
#pragma unroll
        for (int r = 0; r < 4; ++r) {
            float z  = 1.0f / (1.0f + __expf(-accA[0][nt][r]));
            float rg = 1.0f / (1.0f + __expf(-accA[1][nt][r]));
            float hc = accA[2][nt][r] + rg * hh[nt][r];
            hc = hc > 0.f ? hc : 0.2f * hc;
            gout[nt][r] = (1.f - z) * hc + z * (float)hpv16[nt][r];
        }
    }

    // ---- stage output in LDS, then full-line coalesced stores ----
    __syncthreads();   // bar4: proj's warped reads done; reuse smem as ol
#pragma unroll
    for (int nt = 0; nt < 4; ++nt) {
#pragma unroll
        for (int r = 0; r < 4; ++r) {
            int d = 16 * w + quad * 4 + r;
            ol[d * 68 + nt * 16 + ln] = gout[nt][r];
        }
    }
    __syncthreads();   // bar5: ol ready
    {
        const int pixbase = y * HW_ + xh * 64;
#pragma unroll
        for (int it = 0; it < 4; ++it) {
            int idx = tid + it * 256;       // 0..1023
            int ch = idx >> 4, p4 = idx & 15;
            floatx4 v = *(const floatx4*)&ol[ch * 68 + p4 * 4];
            *(floatx4*)&out[(size_t)(b * HID + ch) * NPIX + pixbase + p4 * 4] = v;
        }
    }
}

// ---------------------------------------------------------------------------
extern "C" void kernel_launch(void* const* d_in, const int* in_sizes, int n_in,
                              void* d_out, int out_size, void* d_ws, size_t ws_size,
                              hipStream_t stream)
{
    const float* x      = (const float*)d_in[0];
    const float* hp     = (const float*)d_in[1];
    const float* w_in   = (const float*)d_in[2];
    const float* b_in   = (const float*)d_in[3];
    const float* w_proj = (const float*)d_in[4];
    const float* b_proj = (const float*)d_in[5];
    const float* w_sub  = (const float*)d_in[6];
    const float* b_sub  = (const float*)d_in[7];
    float* out = (float*)d_out;

    // ws layout (bytes), total ~67.4 MB.
    char* ws = (char*)d_ws;
    float*     ccbuf    = (float*)    ws;                 // 16,777,216
    unsigned*  minmax   = (unsigned*) (ws + 16777216);    //        256
    _Float16*  wsub_f16 = (_Float16*)(ws + 16777472);     //     76,800
    float*     bsum     = (float*)    (ws + 16854272);    //      1,024
    _Float16*  win_f16  = (_Float16*)(ws + 16855296);     //    110,592
    _Float16*  wp_f16   = (_Float16*)(ws + 16965888);     //     98,304
    _Float16*  hcl16    = (_Float16*)(ws + 17064192);     // 33,554,432
    _Float16*  xcl16    = (_Float16*)(ws + 50618624);     // 16,777,216

    repack_kernel<<<dim3(559), dim3(256), 0, stream>>>(
        w_in, w_sub, w_proj, b_proj, wsub_f16, bsum, win_f16, wp_f16, minmax);
    transpose_h_kernel<<<dim3(HW_, B_), dim3(256), 0, stream>>>(hp, x, hcl16, xcl16);
    conv_sub_mfma<<<dim3(8, 16, B_), dim3(256), 0, stream>>>(
        xcl16, hcl16, wsub_f16, b_sub, ccbuf, minmax);
    warp_gru_conv<<<dim3(2, HW_, B_), dim3(256), 0, stream>>>(
        hcl16, xcl16, ccbuf, wp_f16, bsum, win_f16, b_in, minmax, out);
}

// Round 8
// 355.724 us; speedup vs baseline: 1.0680x; 1.0680x over previous
//
#include <hip/hip_runtime.h>
#include <hip/hip_bf16.h>
#include <math.h>

// Problem constants
#define B_    16
#define HID   64
#define CIN   32
#define OC1   192   // 3*HID
#define CCC   16    // 2*CONNECTION
#define HW_   128
#define NPIX  (HW_*HW_)

typedef _Float16 half8 __attribute__((ext_vector_type(8)));    // 8 fp16
typedef _Float16 half4 __attribute__((ext_vector_type(4)));    // 4 fp16 (8 B)
typedef float floatx4 __attribute__((ext_vector_type(4)));     // MFMA C/D

// ---- sortable-uint encoding for float atomicMin/Max ----
__device__ __forceinline__ unsigned fenc(float f) {
    unsigned b = __float_as_uint(f);
    return (b & 0x80000000u) ? ~b : (b | 0x80000000u);
}
__device__ __forceinline__ float fdec(unsigned u) {
    unsigned b = (u & 0x80000000u) ? (u ^ 0x80000000u) : ~u;
    return __uint_as_float(b);
}
__device__ __forceinline__ unsigned pack2(float a, float b) {
    union { _Float16 h[2]; unsigned u; } pk;
    pk.h[0] = (_Float16)a; pk.h[1] = (_Float16)b;
    return pk.u;
}

// ---------------------------------------------------------------------------
// K0: repack weights + init minmax
//  wsub_f16[sk=s*3+kc][lane][j] fp16 : A-frags conv_sub (75*64*8)
//  bsum    [o] = sum_i b_proj[i][o]  : 192 fp32
//  win_f16 [s][mt][lane][j] fp16     : A-frags conv_in  (9*12*64*8)
//  wp_f16  [kt][mt][lane][j] fp16    : A-frags warp proj (8*12*64*8)
// ---------------------------------------------------------------------------
__global__ __launch_bounds__(256) void repack_kernel(
    const float* __restrict__ w_in, const float* __restrict__ w_sub,
    const float* __restrict__ w_proj, const float* __restrict__ b_proj,
    _Float16* __restrict__ wsub_f16, float* __restrict__ bsum,
    _Float16* __restrict__ win_f16, _Float16* __restrict__ wp_f16,
    unsigned* __restrict__ minmax)
{
    int idx = blockIdx.x * 256 + threadIdx.x;
    if (idx < 38400) {                       // wsub_f16 frags
        int sk = idx >> 9, r2 = idx & 511;
        int l = r2 >> 3, j = r2 & 7;
        int s = sk / 3, kc = sk - s * 3;
        int ky = s / 5, kx = s - ky * 5;
        int oc = l & 15;
        int icg = kc * 32 + (l >> 4) * 8 + j;
        wsub_f16[idx] = (_Float16)w_sub[oc * 2400 + icg * 25 + ky * 5 + kx];
    } else if (idx < 38400 + 192) {
        int o = idx - 38400;
        bsum[o] = b_proj[o] + b_proj[192 + o] + b_proj[384 + o] + b_proj[576 + o];
    } else if (idx < 38592 + 55296) {        // win_f16
        int j2 = idx - 38592;
        int s = j2 / 6144, r = j2 - s * 6144;
        int mt = r / 512, r2 = r - mt * 512;
        int l = r2 >> 3, j = r2 & 7;
        int oc = mt * 16 + (l & 15);
        int ic = (l >> 4) * 8 + j;
        win_f16[j2] = (_Float16)w_in[oc * 288 + ic * 9 + s];
    } else if (idx < 38592 + 55296 + 49152) { // wp_f16
        int j3 = idx - (38592 + 55296);
        int kt = j3 / 6144, r = j3 - kt * 6144;
        int mt = r / 512, r2 = r - mt * 512;
        int l = r2 >> 3, j = r2 & 7;
        int o = mt * 16 + (l & 15);
        int c_all = kt * 32 + (l >> 4) * 8 + j;
        int i = c_all >> 6, c = c_all & 63;
        wp_f16[j3] = (_Float16)w_proj[(i * 192 + o) * 64 + c];
    }
    if (idx == 0) { minmax[0] = 0xFFFFFFFFu; minmax[1] = 0u; }
}

// ---------------------------------------------------------------------------
// K0c: channels-last fp16 repacks (VECTORIZED R8):
//   hcl16[b][y][x][c 0..63]  from h_prev
//   xcl16[b][y][x][c 0..31]  from x
//   float4 global loads (24 B-ops/thread -> was 72), packed uint2 stores.
//   LDS stride 129 floats: channel-pair reads are 2-way (free) conflicts.
// ---------------------------------------------------------------------------
__global__ __launch_bounds__(256) void transpose_h_kernel(
    const float* __restrict__ hp, const float* __restrict__ x,
    _Float16* __restrict__ hcl, _Float16* __restrict__ xcl)
{
    __shared__ float lds[64 * 129];   // 33024 B
    int tid = threadIdx.x;
    int y = blockIdx.x, b = blockIdx.y;

    // ---- h: 64 ch x 128 px, float4 loads ----
    const float* hb = hp + (size_t)b * HID * NPIX + y * HW_;
#pragma unroll
    for (int it = 0; it < 8; ++it) {
        int idx = tid + it * 256;          // float4 index 0..2047
        int c = idx >> 5, x4 = idx & 31;
        float4 v = *(const float4*)(hb + (size_t)c * NPIX + x4 * 4);
        int base = c * 129 + x4 * 4;
        lds[base] = v.x; lds[base + 1] = v.y; lds[base + 2] = v.z; lds[base + 3] = v.w;
    }
    __syncthreads();
    {
        uint2* o = (uint2*)(hcl + (size_t)((b * HW_ + y) * HW_) * 64);
#pragma unroll
        for (int it = 0; it < 8; ++it) {
            int e2 = tid + it * 256;       // 0..2047 = xx*16 + c4
            int c4 = e2 & 15, xx = e2 >> 4;
            int cb = c4 * 4;
            uint2 pk;
            pk.x = pack2(lds[cb * 129 + xx],       lds[(cb + 1) * 129 + xx]);
            pk.y = pack2(lds[(cb + 2) * 129 + xx], lds[(cb + 3) * 129 + xx]);
            o[e2] = pk;
        }
    }
    __syncthreads();

    // ---- x: 32 ch x 128 px, float4 loads ----
    const float* xb = x + (size_t)b * CIN * NPIX + y * HW_;
#pragma unroll
    for (int it = 0; it < 4; ++it) {
        int idx = tid + it * 256;          // float4 index 0..1023
        int c = idx >> 5, x4 = idx & 31;
        float4 v = *(const float4*)(xb + (size_t)c * NPIX + x4 * 4);
        int base = c * 129 + x4 * 4;
        lds[base] = v.x; lds[base + 1] = v.y; lds[base + 2] = v.z; lds[base + 3] = v.w;
    }
    __syncthreads();
    {
        uint2* ox = (uint2*)(xcl + (size_t)((b * HW_ + y) * HW_) * 32);
#pragma unroll
        for (int it = 0; it < 4; ++it) {
            int e2 = tid + it * 256;       // 0..1023 = xx*8 + c4
            int c4 = e2 & 7, xx = e2 >> 3;
            int cb = c4 * 4;
            uint2 pk;
            pk.x = pack2(lds[cb * 129 + xx],       lds[(cb + 1) * 129 + xx]);
            pk.y = pack2(lds[(cb + 2) * 129 + xx], lds[(cb + 3) * 129 + xx]);
            ox[e2] = pk;
        }
    }
}

// ---------------------------------------------------------------------------
// K1: conv_sub ONLY (5x5, 96->16), fp16 MFMA, staged from channels-last
//   hcl16/xcl16 with fully coalesced uint4 copies.
//   Tile [yy 0..11][xx 0..19][ch 0..95 pad 104]; px stride 208 B.
//   conv_sub: wave w owns px-rows {2w,2w+1}; 25*3*2 = 150 MFMAs.
// ---------------------------------------------------------------------------
__global__ __launch_bounds__(256) void conv_sub_mfma(
    const _Float16* __restrict__ xcl, const _Float16* __restrict__ hcl,
    const _Float16* __restrict__ wsub_f16, const float* __restrict__ b_sub,
    float* __restrict__ cc, unsigned* __restrict__ minmax)
{
    __shared__ __align__(16) _Float16 tile[12 * 20 * 104];  // 49920 B
    __shared__ float redmn[4], redmx[4];
    int tid = threadIdx.x;
    int b = blockIdx.z;
    int y0 = blockIdx.y * 8, x0 = blockIdx.x * 16;

    // ---- stage h channels (ch 32..95): 1920 uint4, coalesced ----
#pragma unroll
    for (int it = 0; it < 8; ++it) {
        int idx = tid + it * 256;
        if (idx < 1920) {
            int yy = idx / 160, rem = idx - yy * 160;
            int px = rem >> 3, q = rem & 7;
            int gy = y0 + yy - 2, gx = x0 + px - 2;
            bool ok = ((unsigned)gy < 128u) & ((unsigned)gx < 128u);
            int cgy = min(max(gy, 0), 127), cgx = min(max(gx, 0), 127);
            uint4 v = ((const uint4*)hcl)[(size_t)((b * 128 + cgy) * 128 + cgx) * 8 + q];
            if (!ok) { v.x = 0; v.y = 0; v.z = 0; v.w = 0; }
            *(uint4*)((char*)tile + (yy * 20 + px) * 208 + 64 + q * 16) = v;
        }
    }
    // ---- stage x channels (ch 0..31): 960 uint4, coalesced ----
#pragma unroll
    for (int it = 0; it < 4; ++it) {
        int idx = tid + it * 256;
        if (idx < 960) {
            int yy = idx / 80, rem = idx - yy * 80;
            int px = rem >> 2, q = rem & 3;
            int gy = y0 + yy - 2, gx = x0 + px - 2;
            bool ok = ((unsigned)gy < 128u) & ((unsigned)gx < 128u);
            int cgy = min(max(gy, 0), 127), cgx = min(max(gx, 0), 127);
            uint4 v = ((const uint4*)xcl)[(size_t)((b * 128 + cgy) * 128 + cgx) * 4 + q];
            if (!ok) { v.x = 0; v.y = 0; v.z = 0; v.w = 0; }
            *(uint4*)((char*)tile + (yy * 20 + px) * 208 + q * 16) = v;
        }
    }
    __syncthreads();

    int w = tid >> 6, l = tid & 63;
    int quad = l >> 4, ln = l & 15;

    floatx4 sinit;
#pragma unroll
    for (int r = 0; r < 4; ++r) sinit[r] = b_sub[quad * 4 + r];
    floatx4 sacc[2] = {sinit, sinit};

#pragma unroll 5
    for (int s = 0; s < 25; ++s) {
        int ky = s / 5, kx = s - (s / 5) * 5;
#pragma unroll
        for (int kc = 0; kc < 3; ++kc) {
            half8 af = *(const half8*)(wsub_f16 + (size_t)((s * 3 + kc) * 64 + l) * 8);
#pragma unroll
            for (int t = 0; t < 2; ++t) {
                int pos = (w * 2 + t + ky) * 20 + (ln + kx);
                half8 bf = *(const half8*)(tile + pos * 104 + kc * 32 + quad * 8);
                sacc[t] = __builtin_amdgcn_mfma_f32_16x16x32_f16(af, bf, sacc[t], 0, 0, 0);
            }
        }
    }

    // epilogue: store cc + fused min/max
    {
        float mn = 1e30f, mx = -1e30f;
#pragma unroll
        for (int t = 0; t < 2; ++t) {
            int yg = y0 + w * 2 + t;
#pragma unroll
            for (int r = 0; r < 4; ++r) {
                int oc = quad * 4 + r;
                float v = sacc[t][r];
                cc[((size_t)(b * CCC + oc) * HW_ + yg) * HW_ + x0 + ln] = v;
                mn = fminf(mn, v); mx = fmaxf(mx, v);
            }
        }
#pragma unroll
        for (int m = 1; m < 64; m <<= 1) {
            mn = fminf(mn, __shfl_xor(mn, m, 64));
            mx = fmaxf(mx, __shfl_xor(mx, m, 64));
        }
        if (l == 0) { redmn[w] = mn; redmx[w] = mx; }
    }
    __syncthreads();
    if (tid == 0) {
        float bmn = fminf(fminf(redmn[0], redmn[1]), fminf(redmn[2], redmn[3]));
        float bmx = fmaxf(fmaxf(redmx[0], redmx[1]), fmaxf(redmx[2], redmx[3]));
        atomicMin(&minmax[0], fenc(bmn));
        atomicMax(&minmax[1], fenc(bmx));
    }
}

// ---------------------------------------------------------------------------
// K3: FUSED conv_in (3x3, 32->192) + grid_sample(4 warps) + MFMA projection
//   + GRU gates. (R7 structure, passed.)
//   R8 tweak: c10/c11 corner loads batched in groups of 4 iterations
//   (8 loads in flight before first use) to shorten the blend phase's
//   latency chain. All indexing identical to R7.
// ---------------------------------------------------------------------------
__global__ __launch_bounds__(256, 3) void warp_gru_conv(
    const _Float16* __restrict__ hcl, const _Float16* __restrict__ xcl,
    const float* __restrict__ cc,
    const _Float16* __restrict__ wp_f16, const float* __restrict__ bsum,
    const _Float16* __restrict__ win_f16, const float* __restrict__ b_in,
    const unsigned* __restrict__ minmax, float* __restrict__ out)
{
    __shared__ __align__(16) _Float16 smem[64 * 256];  // 32768 B; xt/warped/ol
    __shared__ __align__(16) int   mrec[256 * 4];      // 4096 B: per-thread 4 recs
    __shared__ __align__(16) float mw[256 * 4];        // 4096 B: per-thread 4 wts
    _Float16* xt = smem;        // [row 0..2][px 0..71][ic 0..31], swizzled
    _Float16* warped = smem;    // [px 0..63][ch 0..255], swizzled
    float* ol = (float*)smem;   // [ch 0..63][px 0..63], stride 68 floats

    int tid = threadIdx.x;
    int i = tid >> 6;
    int p = tid & 63;
    int b = blockIdx.z, y = blockIdx.y, xh = blockIdx.x;
    int xg = xh * 64 + p;
    int w = i, l = p;
    int quad = l >> 4, ln = l & 15;

    // ---- issue x-tile loads ----
    uint4 xv0, xv1, xv2, xv3;
    int xslot = -1;
    if (tid < 216) {
        int row = tid / 72, px = tid - row * 72;
        int gy = y - 1 + row, gx = xh * 64 - 4 + px;
        bool ok = ((unsigned)gy < 128u) & ((unsigned)gx < 128u);
        int cgy = min(max(gy, 0), 127), cgx = min(max(gx, 0), 127);
        const uint4* s = (const uint4*)(xcl + (size_t)((b * 128 + cgy) * 128 + cgx) * 32);
        xv0 = s[0]; xv1 = s[1]; xv2 = s[2]; xv3 = s[3];
        if (!ok) {
            xv0.x = xv0.y = xv0.z = xv0.w = 0; xv1 = xv0; xv2 = xv0; xv3 = xv0;
        }
        xslot = (row * 72 + px) * 4;
    }

    // ---- gate h_prev loads from hcl16 ----
    const _Float16* hclb = hcl + (size_t)b * NPIX * 64;
    half4 hpv16[4];
    {
        const _Float16* grow = hclb + (size_t)(y * HW_ + xh * 64) * 64 + 16 * w + quad * 4;
#pragma unroll
        for (int nt = 0; nt < 4; ++nt)
            hpv16[nt] = *(const half4*)(grow + (size_t)(nt * 16 + ln) * 64);
    }

    // ---- grid math for own pixel p; stash records + weights in LDS ----
    {
        float mn = fdec(minmax[0]), mx = fdec(minmax[1]);
        float scale = 2.0f / (mx - mn);
        int ccbase = ((b * CCC + 2 * i) * HW_ + y) * HW_ + xg;
        float gxn = (cc[ccbase] - mn) * scale - 1.0f;
        float gyn = (cc[ccbase + NPIX] - mn) * scale - 1.0f;
        float gx = (gxn + 1.0f) * 64.0f - 0.5f;
        float gy = (gyn + 1.0f) * 64.0f - 0.5f;
        float x0f = floorf(gx), y0f = floorf(gy);
        float wx1 = gx - x0f, wy1 = gy - y0f;
        float wx0 = 1.0f - wx1, wy0 = 1.0f - wy1;
        int ix0 = (int)x0f, iy0 = (int)y0f;
        int ix1 = ix0 + 1, iy1 = iy0 + 1;
        bool vx0 = (unsigned)ix0 < 128u, vx1 = (unsigned)ix1 < 128u;
        bool vy0 = (unsigned)iy0 < 128u, vy1 = (unsigned)iy1 < 128u;
        float w00 = (vx0 && vy0) ? wy0 * wx0 : 0.f;
        float w01 = (vx1 && vy0) ? wy0 * wx1 : 0.f;
        float w10 = (vx0 && vy1) ? wy1 * wx0 : 0.f;
        float w11 = (vx1 && vy1) ? wy1 * wx1 : 0.f;
        int cx0 = min(max(ix0, 0), 127), cx1 = min(max(ix1, 0), 127);
        int cy0 = min(max(iy0, 0), 127), cy1 = min(max(iy1, 0), 127);
        int* mr = &mrec[tid * 4];
        mr[0] = cy0 * HW_ + cx0; mr[1] = cy0 * HW_ + cx1;
        mr[2] = cy1 * HW_ + cx0; mr[3] = cy1 * HW_ + cx1;
        float* mwp = &mw[tid * 4];
        mwp[0] = w00; mwp[1] = w01; mwp[2] = w10; mwp[3] = w11;
    }

    // ---- write x tile (swizzled) ----
    if (xslot >= 0) {
        unsigned b0 = (unsigned)(xslot * 16);
        unsigned by0_ = b0 ^ (((b0 >> 7) & 3) << 4);
        unsigned b1 = (unsigned)((xslot + 1) * 16);
        unsigned by1_ = b1 ^ (((b1 >> 7) & 3) << 4);
        unsigned b2 = (unsigned)((xslot + 2) * 16);
        unsigned by2_ = b2 ^ (((b2 >> 7) & 3) << 4);
        unsigned b3 = (unsigned)((xslot + 3) * 16);
        unsigned by3_ = b3 ^ (((b3 >> 7) & 3) << 4);
        *(uint4*)((char*)xt + by0_) = xv0;
        *(uint4*)((char*)xt + by1_) = xv1;
        *(uint4*)((char*)xt + by2_) = xv2;
        *(uint4*)((char*)xt + by3_) = xv3;
    }
    __syncthreads();   // bar1: xt + mrec/mw ready

    // ---- structured gather, corners 00/01 (hoisted above conv_in) ----
    int sub = p >> 3;          // pixel sub-index within each iteration
    int e   = p & 7;           // 16-B chunk within the 128-B record
    half8 g0[8], g1[8];
#pragma unroll
    for (int it = 0; it < 8; ++it) {
        int pp = it * 8 + sub;
        const int* mr = &mrec[(i * 64 + pp) * 4];
        int r0 = mr[0], r1 = mr[1];
        g0[it] = *(const half8*)(hclb + (size_t)r0 * 64 + e * 8);
        g1[it] = *(const half8*)(hclb + (size_t)r1 * 64 + e * 8);
    }

    // ---- accumulators: z,r shared between conv_in and proj; h split ----
    floatx4 accA[3][4];   // [0]=z sum, [1]=r sum, [2]=x_h
    floatx4 hh[4];        // h_h (proj)
#pragma unroll
    for (int t = 0; t < 2; ++t) {
        floatx4 bi = *(const floatx4*)(b_in + t * 64 + 16 * w + quad * 4);
        floatx4 bs = *(const floatx4*)(bsum + t * 64 + 16 * w + quad * 4);
        floatx4 init;
#pragma unroll
        for (int r = 0; r < 4; ++r) init[r] = bi[r] + bs[r];
#pragma unroll
        for (int nt = 0; nt < 4; ++nt) accA[t][nt] = init;
    }
    {
        floatx4 bih = *(const floatx4*)(b_in + 128 + 16 * w + quad * 4);
        floatx4 bsh = *(const floatx4*)(bsum + 128 + 16 * w + quad * 4);
#pragma unroll
        for (int nt = 0; nt < 4; ++nt) { accA[2][nt] = bih; hh[nt] = bsh; }
    }

    // ---- conv_in: 9 taps x 3 m-tiles x 4 n-tiles = 108 MFMA ----
#pragma unroll
    for (int s = 0; s < 9; ++s) {
        int ky = s / 3, kx = s - ky * 3;
        half8 af[3];
#pragma unroll
        for (int t = 0; t < 3; ++t)
            af[t] = *(const half8*)(win_f16 + (size_t)((s * 12 + (t * 4 + w)) * 64 + l) * 8);
#pragma unroll
        for (int nt = 0; nt < 4; ++nt) {
            int pxr = ky * 72 + nt * 16 + ln + kx + 3;
            unsigned byte = (unsigned)(pxr * 64 + quad * 16);
            byte ^= ((byte >> 7) & 3) << 4;
            half8 bf = *(const half8*)((char*)xt + byte);
#pragma unroll
            for (int t = 0; t < 3; ++t)
                accA[t][nt] = __builtin_amdgcn_mfma_f32_16x16x32_f16(af[t], bf, accA[t][nt], 0, 0, 0);
        }
    }
    __syncthreads();   // bar2: all xt reads done; safe to overwrite with warped

    // ---- structured gather corners 10/11 (batched x4) + blend + write ----
#pragma unroll
    for (int h = 0; h < 2; ++h) {
        half8 c10a[4], c11a[4];
#pragma unroll
        for (int it2 = 0; it2 < 4; ++it2) {
            int it = h * 4 + it2;
            int pp = it * 8 + sub;
            const int* mr = &mrec[(i * 64 + pp) * 4];
            c10a[it2] = *(const half8*)(hclb + (size_t)mr[2] * 64 + e * 8);
            c11a[it2] = *(const half8*)(hclb + (size_t)mr[3] * 64 + e * 8);
        }
#pragma unroll
        for (int it2 = 0; it2 < 4; ++it2) {
            int it = h * 4 + it2;
            int pp = it * 8 + sub;
            const float* mwp = &mw[(i * 64 + pp) * 4];
            _Float16 f00 = (_Float16)mwp[0];
            _Float16 f01 = (_Float16)mwp[1];
            _Float16 f10 = (_Float16)mwp[2];
            _Float16 f11 = (_Float16)mwp[3];
            half8 v = g0[it] * f00 + g1[it] * f01 + c10a[it2] * f10 + c11a[it2] * f11;
            int cs = (i * 8 + e) ^ sub;
            *(half8*)(warped + pp * 256 + cs * 8) = v;
        }
    }
    __syncthreads();   // bar3: warped ready

    // ---- warp projection: 8 kt x 3 m x 4 n = 96 MFMA ----
#pragma unroll
    for (int kt = 0; kt < 8; ++kt) {
        half8 af[3];
#pragma unroll
        for (int t = 0; t < 3; ++t)
            af[t] = *(const half8*)(wp_f16 + (size_t)((kt * 12 + (t * 4 + w)) * 64 + l) * 8);
#pragma unroll
        for (int nt = 0; nt < 4; ++nt) {
            int pxi = nt * 16 + ln;
            int cs = (kt * 4 + quad) ^ (pxi & 7);
            half8 bf = *(const half8*)(warped + pxi * 256 + cs * 8);
            accA[0][nt] = __builtin_amdgcn_mfma_f32_16x16x32_f16(af[0], bf, accA[0][nt], 0, 0, 0);
            accA[1][nt] = __builtin_amdgcn_mfma_f32_16x16x32_f16(af[1], bf, accA[1][nt], 0, 0, 0);
            hh[nt]      = __builtin_amdgcn_mfma_f32_16x16x32_f16(af[2], bf, hh[nt], 0, 0, 0);
        }
    }

    // ---- gates (all register inputs) ----
    float gout[4][4];
#pragma unroll
    for (int nt = 0; nt < 4; ++nt) {
#pragma unroll
        for (int r = 0; r < 4; ++r) {
            float z  = 1.0f / (1.0f + __expf(-accA[0][nt][r]));
            float rg = 1.0f / (1.0f + __expf(-accA[1][nt][r]));
            float hc = accA[2][nt][r] + rg * hh[nt][r];
            hc = hc > 0.f ? hc : 0.2f * hc;
            gout[nt][r] = (1.f - z) * hc + z * (float)hpv16[nt][r];
        }
    }

    // ---- stage output in LDS, then full-line coalesced stores ----
    __syncthreads();   // bar4: proj's warped reads done; reuse smem as ol
#pragma unroll
    for (int nt = 0; nt < 4; ++nt) {
#pragma unroll
        for (int r = 0; r < 4; ++r) {
            int d = 16 * w + quad * 4 + r;
            ol[d * 68 + nt * 16 + ln] = gout[nt][r];
        }
    }
    __syncthreads();   // bar5: ol ready
    {
        const int pixbase = y * HW_ + xh * 64;
#pragma unroll
        for (int it = 0; it < 4; ++it) {
            int idx = tid + it * 256;       // 0..1023
            int ch = idx >> 4, p4 = idx & 15;
            floatx4 v = *(const floatx4*)&ol[ch * 68 + p4 * 4];
            *(floatx4*)&out[(size_t)(b * HID + ch) * NPIX + pixbase + p4 * 4] = v;
        }
    }
}

// ---------------------------------------------------------------------------
extern "C" void kernel_launch(void* const* d_in, const int* in_sizes, int n_in,
                              void* d_out, int out_size, void* d_ws, size_t ws_size,
                              hipStream_t stream)
{
    const float* x      = (const float*)d_in[0];
    const float* hp     = (const float*)d_in[1];
    const float* w_in   = (const float*)d_in[2];
    const float* b_in   = (const float*)d_in[3];
    const float* w_proj = (const float*)d_in[4];
    const float* b_proj = (const float*)d_in[5];
    const float* w_sub  = (const float*)d_in[6];
    const float* b_sub  = (const float*)d_in[7];
    float* out = (float*)d_out;

    // ws layout (bytes), total ~67.4 MB.
    char* ws = (char*)d_ws;
    float*     ccbuf    = (float*)    ws;                 // 16,777,216
    unsigned*  minmax   = (unsigned*) (ws + 16777216);    //        256
    _Float16*  wsub_f16 = (_Float16*)(ws + 16777472);     //     76,800
    float*     bsum     = (float*)    (ws + 16854272);    //      1,024
    _Float16*  win_f16  = (_Float16*)(ws + 16855296);     //    110,592
    _Float16*  wp_f16   = (_Float16*)(ws + 16965888);     //     98,304
    _Float16*  hcl16    = (_Float16*)(ws + 17064192);     // 33,554,432
    _Float16*  xcl16    = (_Float16*)(ws + 50618624);     // 16,777,216

    repack_kernel<<<dim3(559), dim3(256), 0, stream>>>(
        w_in, w_sub, w_proj, b_proj, wsub_f16, bsum, win_f16, wp_f16, minmax);
    transpose_h_kernel<<<dim3(HW_, B_), dim3(256), 0, stream>>>(hp, x, hcl16, xcl16);
    conv_sub_mfma<<<dim3(8, 16, B_), dim3(256), 0, stream>>>(
        xcl16, hcl16, wsub_f16, b_sub, ccbuf, minmax);
    warp_gru_conv<<<dim3(2, HW_, B_), dim3(256), 0, stream>>>(
        hcl16, xcl16, ccbuf, wp_f16, bsum, win_f16, b_in, minmax, out);
}